// Round 1
// baseline (234.090 us; speedup 1.0000x reference)
//
#include <hip/hip_runtime.h>

// GraphPooling: B=8, N=3072, D=1024, POOL=3, steps=1024
//  out[b, 2k,   d] = (sum x[b, s..e, d]) / (e-s+1) + 0.006   (s,e from graph[b,k])
//  out[b, 2k+1, d] = mean(x[b, 3k:3k+3, d])
//
// One block = one (b, 8-column d-tile). Full per-column prefix array lives in
// LDS (skewed layout, conflict-free writes); x is read exactly once from HBM.

constexpr int Bdim  = 8;
constexpr int Nn    = 3072;
constexpr int Dd    = 1024;
constexpr int STEPS = 1024;   // N / POOL
constexpr int T     = 8;      // d-columns per block
constexpr int SEGS  = 32;     // scan segments (threads per column)
constexpr int CHUNK = 96;     // Nn / SEGS rows per thread
constexpr int SSTR  = 3112;   // LDS column stride (dwords): >= 3073+33, == 8 mod 32
constexpr float EPS = 0.006f;

__global__ __launch_bounds__(256, 1)
void GraphPooling_kernel(const float* __restrict__ x,
                         const int*   __restrict__ graph,
                         float*       __restrict__ out) {
    // c_lds: per-column prefix c[0..3072] at phys = idx + idx/CHUNK (skewed)
    __shared__ float c_lds[T * SSTR];          // 99584 B
    __shared__ float part[T][SEGS + 1];        //  1056 B
    __shared__ int   gbuf[2 * STEPS];          //  8192 B

    const int tid = threadIdx.x;
    const int b   = blockIdx.y;
    const int d0  = blockIdx.x * T;
    const int col = tid & (T - 1);
    const int seg = tid >> 3;                  // 0..31

    // stage graph[b] (2048 int32) into LDS, coalesced
    const int* gsrc = graph + b * 2 * STEPS;
    for (int i = tid; i < 2 * STEPS; i += 256) gbuf[i] = gsrc[i];

    // ---- phase 1: load 96 rows of one column into registers; local sum;
    //              window means written directly (odd output rows) ----
    const float* xb = x + ((size_t)b * Nn) * Dd + d0 + col;
    const size_t row0 = (size_t)(seg * CHUNK) * Dd;
    float v[CHUNK];
    float lsum = 0.f;
#pragma unroll
    for (int i = 0; i < CHUNK; ++i) {
        v[i] = xb[row0 + (size_t)i * Dd];
        lsum += v[i];
    }
    float* ob = out + ((size_t)b * 2 * STEPS) * Dd + d0 + col;
#pragma unroll
    for (int w = 0; w < CHUNK / 3; ++w) {
        float wm = (v[3 * w] + v[3 * w + 1] + v[3 * w + 2]) * (1.f / 3.f);
        int k = seg * (CHUNK / 3) + w;
        ob[(size_t)(2 * k + 1) * Dd] = wm;
    }
    part[col][seg] = lsum;
    __syncthreads();

    // ---- phase 2: exclusive scan of 32 partials per column (8 threads) ----
    if (tid < T) {
        float run = 0.f;
#pragma unroll
        for (int s2 = 0; s2 < SEGS; ++s2) {
            float t2 = part[tid][s2];
            part[tid][s2] = run;
            run += t2;
        }
    }
    __syncthreads();

    // ---- phase 3: write skewed prefix array into LDS ----
    // bank(write) = 8*col + seg + i + 1 (mod 32) -> 2 lanes/bank, conflict-free
    float run = part[col][seg];
    float* cb = c_lds + col * SSTR;
    if (seg == 0) cb[0] = 0.f;                 // c[0] = 0
#pragma unroll
    for (int i = 0; i < CHUNK; ++i) {
        run += v[i];
        int cidx = seg * CHUNK + i + 1;        // inclusive prefix of row n -> c[n+1]
        cb[cidx + cidx / CHUNK] = run;
    }
    __syncthreads();

    // ---- phase 4: gather segment means (even output rows) ----
    const int krow = seg;                      // 0..31
#pragma unroll 4
    for (int j = 0; j < STEPS / SEGS; ++j) {
        int k = krow + SEGS * j;
        int s = gbuf[2 * k];                   // broadcast across the 8 cols
        int e = gbuf[2 * k + 1];
        float cs = cb[s + s / CHUNK];
        int   ei = e + 1;
        float ce = cb[ei + ei / CHUNK];
        float sm = (ce - cs) / (float)(e - s + 1) + EPS;
        ob[(size_t)(2 * k) * Dd] = sm;
    }
}

extern "C" void kernel_launch(void* const* d_in, const int* in_sizes, int n_in,
                              void* d_out, int out_size, void* d_ws, size_t ws_size,
                              hipStream_t stream) {
    const float* x     = (const float*)d_in[0];
    const int*   graph = (const int*)d_in[1];
    float*       out   = (float*)d_out;

    dim3 grid(Dd / T, Bdim);   // (128, 8): d-tile fastest -> co-resident tiles share rows
    dim3 block(256);
    GraphPooling_kernel<<<grid, block, 0, stream>>>(x, graph, out);
}

// Round 2
// 217.351 us; speedup vs baseline: 1.0770x; 1.0770x over previous
//
#include <hip/hip_runtime.h>

// GraphPooling: B=8, N=3072, D=1024, POOL=3, steps=1024
//  out[b, 2k,   d] = (sum x[b, s..e, d]) / (e-s+1) + 0.006
//  out[b, 2k+1, d] = mean(x[b, 3k:3k+3, d])
//
// Round-2 design: chunked scan via HBM workspace.
//   K1: streaming scan, 256 contiguous d-cols/block (coalesced, no over-fetch):
//       writes c_local (exclusive prefix within 96-row chunk), chunk totals P,
//       and the window means (odd output rows).
//   K3: per-block rebuilds 33-entry chunk prefix O from P (L2-hot), gathers
//       c[idx] = O[idx/96] + c_local[idx] at rows s, e+1 (L3-warm), writes
//       segment means (even output rows).

constexpr int Bdim  = 8;
constexpr int Nn    = 3072;
constexpr int Dd    = 1024;
constexpr int STEPS = 1024;
constexpr int CH    = 96;    // rows per scan chunk (divisible by POOL=3)
constexpr int NCH   = 32;    // Nn / CH
constexpr int KT    = 64;    // steps per K3 block
constexpr int NKT   = 16;    // STEPS / KT
constexpr float EPS = 0.006f;

constexpr size_t C_ELEMS = (size_t)Bdim * Nn * Dd;    // c_local
constexpr size_t P_ELEMS = (size_t)Bdim * NCH * Dd;   // chunk totals
constexpr size_t WS_NEED = (C_ELEMS + P_ELEMS) * sizeof(float);

// ---------------- K1: chunked scan + window means ----------------
__global__ __launch_bounds__(256)
void k1_scan(const float* __restrict__ x, float* __restrict__ out,
             float* __restrict__ c_local, float* __restrict__ P) {
    const int tid = threadIdx.x;
    const int d   = blockIdx.x * 256 + tid;   // 4 d-tiles
    const int ch  = blockIdx.y;               // 32 chunks
    const int b   = blockIdx.z;               // 8 batches
    const int r0  = ch * CH;

    const float* xp = x       + ((size_t)(b * Nn + r0)) * Dd + d;
    float*       cp = c_local + ((size_t)(b * Nn + r0)) * Dd + d;
    float*       op = out     + ((size_t)b * 2 * STEPS) * Dd + d;
    const int k0 = r0 / 3;                    // first window index in chunk

    float run = 0.f;
#pragma unroll 4
    for (int w = 0; w < CH / 3; ++w) {
        float base = run;
        float v0 = xp[(size_t)(3 * w + 0) * Dd];
        float v1 = xp[(size_t)(3 * w + 1) * Dd];
        float v2 = xp[(size_t)(3 * w + 2) * Dd];
        cp[(size_t)(3 * w + 0) * Dd] = run; run += v0;
        cp[(size_t)(3 * w + 1) * Dd] = run; run += v1;
        cp[(size_t)(3 * w + 2) * Dd] = run; run += v2;
        op[(size_t)(2 * (k0 + w) + 1) * Dd] = (run - base) * (1.f / 3.f);
    }
    P[((size_t)b * NCH + ch) * Dd + d] = run;
}

// ---------------- K3: gather segment means ----------------
__global__ __launch_bounds__(256)
void k3_gather(const float* __restrict__ c_local, const float* __restrict__ P,
               const int* __restrict__ graph, float* __restrict__ out) {
    __shared__ float O[NCH + 1][256];   // 33 KB: chunk-prefix per column
    __shared__ int   gbuf[2 * KT];

    const int tid = threadIdx.x;
    const int d   = blockIdx.x * 256 + tid;
    const int kt  = blockIdx.y;
    const int b   = blockIdx.z;

    const int* gs = graph + ((size_t)(b * STEPS + kt * KT)) * 2;
    for (int i = tid; i < 2 * KT; i += 256) gbuf[i] = gs[i];

    const float* Pp = P + (size_t)b * NCH * Dd + d;
    float run = 0.f;
#pragma unroll
    for (int ch = 0; ch < NCH; ++ch) {
        O[ch][tid] = run;
        run += Pp[(size_t)ch * Dd];
    }
    O[NCH][tid] = run;
    __syncthreads();

    const float* cb = c_local + (size_t)b * Nn * Dd + d;
    float*       ob = out     + (size_t)b * 2 * STEPS * Dd + d;

#pragma unroll 4
    for (int j = 0; j < KT; ++j) {
        int s  = gbuf[2 * j];
        int e  = gbuf[2 * j + 1];
        int e1 = e + 1;
        float cs = O[s / CH][tid] + cb[(size_t)s * Dd];
        float ce;
        if (e1 < Nn) ce = O[e1 / CH][tid] + cb[(size_t)e1 * Dd];
        else         ce = O[NCH][tid];
        int k = kt * KT + j;
        ob[(size_t)(2 * k) * Dd] = (ce - cs) / (float)(e - s + 1) + EPS;
    }
}

// ---------------- Round-1 fused fallback (if ws too small) ----------------
constexpr int T    = 8;
constexpr int SEGS = 32;
constexpr int FCH  = 96;
constexpr int SSTR = 3112;

__global__ __launch_bounds__(256, 1)
void fused_fallback(const float* __restrict__ x, const int* __restrict__ graph,
                    float* __restrict__ out) {
    __shared__ float c_lds[T * SSTR];
    __shared__ float part[T][SEGS + 1];
    __shared__ int   gbuf[2 * STEPS];

    const int tid = threadIdx.x;
    const int b   = blockIdx.y;
    const int d0  = blockIdx.x * T;
    const int col = tid & (T - 1);
    const int seg = tid >> 3;

    const int* gsrc = graph + b * 2 * STEPS;
    for (int i = tid; i < 2 * STEPS; i += 256) gbuf[i] = gsrc[i];

    const float* xb = x + ((size_t)b * Nn) * Dd + d0 + col;
    const size_t row0 = (size_t)(seg * FCH) * Dd;
    float v[FCH];
    float lsum = 0.f;
#pragma unroll
    for (int i = 0; i < FCH; ++i) {
        v[i] = xb[row0 + (size_t)i * Dd];
        lsum += v[i];
    }
    float* ob = out + ((size_t)b * 2 * STEPS) * Dd + d0 + col;
#pragma unroll
    for (int w = 0; w < FCH / 3; ++w) {
        float wm = (v[3 * w] + v[3 * w + 1] + v[3 * w + 2]) * (1.f / 3.f);
        int k = seg * (FCH / 3) + w;
        ob[(size_t)(2 * k + 1) * Dd] = wm;
    }
    part[col][seg] = lsum;
    __syncthreads();

    if (tid < T) {
        float run = 0.f;
#pragma unroll
        for (int s2 = 0; s2 < SEGS; ++s2) {
            float t2 = part[tid][s2];
            part[tid][s2] = run;
            run += t2;
        }
    }
    __syncthreads();

    float run = part[col][seg];
    float* cb = c_lds + col * SSTR;
    if (seg == 0) cb[0] = 0.f;
#pragma unroll
    for (int i = 0; i < FCH; ++i) {
        run += v[i];
        int cidx = seg * FCH + i + 1;
        cb[cidx + cidx / FCH] = run;
    }
    __syncthreads();

#pragma unroll 4
    for (int j = 0; j < STEPS / SEGS; ++j) {
        int k = seg + SEGS * j;
        int s = gbuf[2 * k];
        int e = gbuf[2 * k + 1];
        float cs = cb[s + s / FCH];
        int   ei = e + 1;
        float ce = cb[ei + ei / FCH];
        ob[(size_t)(2 * k) * Dd] = (ce - cs) / (float)(e - s + 1) + EPS;
    }
}

extern "C" void kernel_launch(void* const* d_in, const int* in_sizes, int n_in,
                              void* d_out, int out_size, void* d_ws, size_t ws_size,
                              hipStream_t stream) {
    const float* x     = (const float*)d_in[0];
    const int*   graph = (const int*)d_in[1];
    float*       out   = (float*)d_out;

    if (ws_size >= WS_NEED) {
        float* c_local = (float*)d_ws;
        float* P       = (float*)d_ws + C_ELEMS;
        dim3 g1(Dd / 256, NCH, Bdim);   // (4, 32, 8) = 1024 blocks
        k1_scan<<<g1, 256, 0, stream>>>(x, out, c_local, P);
        dim3 g3(Dd / 256, NKT, Bdim);   // (4, 16, 8) = 512 blocks
        k3_gather<<<g3, 256, 0, stream>>>(c_local, P, graph, out);
    } else {
        dim3 grid(Dd / T, Bdim);
        fused_fallback<<<grid, 256, 0, stream>>>(x, graph, out);
    }
}

// Round 3
// 210.383 us; speedup vs baseline: 1.1127x; 1.0331x over previous
//
#include <hip/hip_runtime.h>

// GraphPooling: B=8, N=3072, D=1024, POOL=3, steps=1024
//  out[b, 2k,   d] = (sum x[b, s..e, d]) / (e-s+1) + 0.006
//  out[b, 2k+1, d] = mean(x[b, 3k:3k+3, d])
//
// Round-3: window-granularity hierarchy, float4 (16 B/lane) everywhere.
//  K1: per 8-window chunk: window sums w, odd-row means (=w/3), exclusive
//      within-chunk prefix Wl[m] (32 MB), chunk totals P[ch] (4 MB).
//  K2: tiny scan P -> exclusive chunk prefix O (129 entries/b/d).
//  K3: gather c[idx] = O[m>>3] + Wl[m] + (r>0? x[3m]) + (r>1? x[3m+1]),
//      m = idx/3, r = idx%3; idx==N uses O[128] (total). All rows coalesced.

constexpr int Bdim  = 8;
constexpr int Nn    = 3072;
constexpr int Dd    = 1024;
constexpr int STEPS = 1024;   // windows
constexpr int CHW   = 8;      // windows per chunk
constexpr int NCH   = 128;    // STEPS / CHW
constexpr int KT    = 16;     // steps per K3 block
constexpr int NKT   = 64;     // STEPS / KT
constexpr int D4    = Dd / 4; // 256 float4 per row
constexpr float EPS = 0.006f;

constexpr size_t WL_E = (size_t)Bdim * STEPS * Dd;        // 32 MB
constexpr size_t P_E  = (size_t)Bdim * NCH * Dd;          //  4 MB
constexpr size_t O_E  = (size_t)Bdim * (NCH + 1) * Dd;    //  4.03 MB

__device__ __forceinline__ float4 f4add(float4 a, float4 b) {
    return make_float4(a.x + b.x, a.y + b.y, a.z + b.z, a.w + b.w);
}

// ---------------- K1: window sums + within-chunk prefix ----------------
__global__ __launch_bounds__(256, 4)
void k1_scan(const float4* __restrict__ x4, float4* __restrict__ out4,
             float4* __restrict__ Wl4, float4* __restrict__ P4) {
    const int t  = threadIdx.x;          // float4 column 0..255
    const int ch = blockIdx.x;           // 0..127
    const int b  = blockIdx.y;           // 0..7
    const int k0 = ch * CHW;             // first window of chunk
    const int r0 = k0 * 3;               // first row of chunk

    const float4* xp = x4   + ((size_t)(b * Nn + r0)) * D4 + t;
    float4*       wl = Wl4  + ((size_t)(b * STEPS + k0)) * D4 + t;
    float4*       op = out4 + ((size_t)b * 2 * STEPS) * D4 + t;

    float4 run = make_float4(0.f, 0.f, 0.f, 0.f);
#pragma unroll
    for (int w = 0; w < CHW; ++w) {
        wl[(size_t)w * D4] = run;                       // exclusive prefix
        float4 v0 = xp[(size_t)(3 * w + 0) * D4];
        float4 v1 = xp[(size_t)(3 * w + 1) * D4];
        float4 v2 = xp[(size_t)(3 * w + 2) * D4];
        float4 s3 = f4add(f4add(v0, v1), v2);
        float4 wm = make_float4(s3.x * (1.f / 3.f), s3.y * (1.f / 3.f),
                                s3.z * (1.f / 3.f), s3.w * (1.f / 3.f));
        op[(size_t)(2 * (k0 + w) + 1) * D4] = wm;       // odd output row
        run = f4add(run, s3);
    }
    P4[((size_t)b * NCH + ch) * D4 + t] = run;
}

// ---------------- K2: scan chunk totals -> exclusive chunk prefix ----------------
__global__ __launch_bounds__(128)
void k2_chscan(const float* __restrict__ P, float* __restrict__ O) {
    const int d = blockIdx.x * 128 + threadIdx.x;   // 8 tiles of 128 cols
    const int b = blockIdx.y;
    const float* p = P + (size_t)b * NCH * Dd + d;
    float*       o = O + (size_t)b * (NCH + 1) * Dd + d;
    float run = 0.f;
#pragma unroll 8
    for (int ch = 0; ch < NCH; ++ch) {
        o[(size_t)ch * Dd] = run;
        run += p[(size_t)ch * Dd];
    }
    o[(size_t)NCH * Dd] = run;                      // total = c[N]
}

// ---------------- K3: gather segment means ----------------
__global__ __launch_bounds__(256, 2)
void k3_gather(const float4* __restrict__ x4, const float4* __restrict__ Wl4,
               const float4* __restrict__ O4, const int* __restrict__ graph,
               float4* __restrict__ out4) {
    __shared__ int gbuf[2 * KT];
    const int t  = threadIdx.x;
    const int kt = blockIdx.x;
    const int b  = blockIdx.y;

    const int* gs = graph + ((size_t)(b * STEPS + kt * KT)) * 2;
    if (t < 2 * KT) gbuf[t] = gs[t];
    __syncthreads();

    const float4* xb = x4  + (size_t)b * Nn * D4 + t;
    const float4* wl = Wl4 + (size_t)b * STEPS * D4 + t;
    const float4* oc = O4  + (size_t)b * (NCH + 1) * D4 + t;
    float4*       ob = out4 + (size_t)b * 2 * STEPS * D4 + t;

#pragma unroll 4
    for (int j = 0; j < KT; ++j) {
        int s = gbuf[2 * j];
        int e = gbuf[2 * j + 1];

        int m1 = s / 3, r1 = s - 3 * m1;            // s <= N-1 -> m1 <= 1023
        float4 cs = f4add(oc[(size_t)(m1 >> 3) * D4], wl[(size_t)m1 * D4]);
        if (r1 > 0) cs = f4add(cs, xb[(size_t)(3 * m1) * D4]);
        if (r1 > 1) cs = f4add(cs, xb[(size_t)(3 * m1 + 1) * D4]);

        int ie = e + 1;                             // 1..N
        float4 ce;
        if (ie == Nn) {
            ce = oc[(size_t)NCH * D4];
        } else {
            int m2 = ie / 3, r2 = ie - 3 * m2;
            ce = f4add(oc[(size_t)(m2 >> 3) * D4], wl[(size_t)m2 * D4]);
            if (r2 > 0) ce = f4add(ce, xb[(size_t)(3 * m2) * D4]);
            if (r2 > 1) ce = f4add(ce, xb[(size_t)(3 * m2 + 1) * D4]);
        }

        float inv = 1.f / (float)(e - s + 1);
        float4 res = make_float4((ce.x - cs.x) * inv + EPS,
                                 (ce.y - cs.y) * inv + EPS,
                                 (ce.z - cs.z) * inv + EPS,
                                 (ce.w - cs.w) * inv + EPS);
        int k = kt * KT + j;
        ob[(size_t)(2 * k) * D4] = res;             // even output row
    }
}

extern "C" void kernel_launch(void* const* d_in, const int* in_sizes, int n_in,
                              void* d_out, int out_size, void* d_ws, size_t ws_size,
                              hipStream_t stream) {
    const float* x     = (const float*)d_in[0];
    const int*   graph = (const int*)d_in[1];
    float*       out   = (float*)d_out;

    float* Wl = (float*)d_ws;
    float* P  = Wl + WL_E;
    float* O  = P + P_E;

    dim3 g1(NCH, Bdim);          // (128, 8) = 1024 blocks
    k1_scan<<<g1, 256, 0, stream>>>((const float4*)x, (float4*)out,
                                    (float4*)Wl, (float4*)P);
    dim3 g2(Dd / 128, Bdim);     // (8, 8) = 64 blocks
    k2_chscan<<<g2, 128, 0, stream>>>(P, O);
    dim3 g3(NKT, Bdim);          // (64, 8) = 512 blocks
    k3_gather<<<g3, 256, 0, stream>>>((const float4*)x, (const float4*)Wl,
                                      (const float4*)O, graph, (float4*)out);
}